// Round 2
// baseline (2310.178 us; speedup 1.0000x reference)
//
#include <hip/hip_runtime.h>
#include <hip/hip_bf16.h>

typedef __hip_bfloat16 bf16;

#define Bc 2
#define Nc 512
#define Rc 64
#define Tc 128
#define Ec 64
#define Hc 8
#define THc 1024
#define FFc 256

__device__ __forceinline__ bf16  f2b(float x){ return __float2bfloat16(x); }
__device__ __forceinline__ float us2f(unsigned short u){
  union { unsigned int i; float f; } c; c.i = ((unsigned int)u) << 16; return c.f;
}
__device__ __forceinline__ float clip5(float x){ return fminf(fmaxf(x, -5.0f), 5.0f); }

__device__ __forceinline__ float wave_max64(float v){
#pragma unroll
  for (int o = 32; o > 0; o >>= 1) v = fmaxf(v, __shfl_xor(v, o, 64));
  return v;
}
__device__ __forceinline__ float wave_sum64(float v){
#pragma unroll
  for (int o = 32; o > 0; o >>= 1) v += __shfl_xor(v, o, 64);
  return v;
}

// ---------------- prep: ds = D_S@W_emb + b_emb ; qhat_sr = I_param(head)@Wq_sr ----
__global__ __launch_bounds__(64) void k_prep(
    const float* __restrict__ DS, const float* __restrict__ Wemb,
    const float* __restrict__ bemb, const float* __restrict__ Ip,
    const float* __restrict__ Wq, float* __restrict__ ds, float* __restrict__ qhat)
{
  int bid = blockIdx.x, t = threadIdx.x;
  if (bid < Nc){
    int n = bid, e = t;
    __shared__ float row[Rc];
    row[t] = DS[n*Rc + t];
    __syncthreads();
    float acc = bemb[e];
    for (int r = 0; r < Rc; ++r) acc += row[r] * Wemb[r*Ec + e];
    ds[n*Ec + e] = acc;
  } else {
    int r = bid - Nc;
    __shared__ float irow[Ec];
    irow[t] = Ip[r*Ec + t];
    __syncthreads();
    int h = t >> 3, d = t & 7;
    float acc = 0.0f;
#pragma unroll
    for (int d0 = 0; d0 < 8; ++d0) acc += irow[h*8 + d0] * Wq[d0*8 + d];
    qhat[r*Ec + h*8 + d] = acc;   // [R][H][D]
  }
}

// ---------------- khat_sr = (key+ds)@Wk per head; vhat_sr = value@Wv --------------
__global__ __launch_bounds__(256) void k_proj_sr(
    const float* __restrict__ key, const float* __restrict__ value,
    const float* __restrict__ ds, const float* __restrict__ Wk,
    const float* __restrict__ Wv, float* __restrict__ khat, float* __restrict__ vhat)
{
  __shared__ float wk[64], wv[64];
  int t = threadIdx.x;
  if (t < 64){ wk[t] = Wk[t]; wv[t] = Wv[t]; }
  __syncthreads();
  int u = blockIdx.x*256 + t;              // (b,n,t,h) unit, < 1048576
  int h = u & 7;
  int nt = u >> 3;                         // (b*N+n)*T + t
  int n = (nt / Tc) % Nc;
  const float* kp = key + (size_t)u*8;
  const float* vp = value + (size_t)u*8;
  const float* dsp = ds + n*Ec + h*8;
  float kin[8], vin[8];
#pragma unroll
  for (int d = 0; d < 8; ++d){ kin[d] = kp[d] + dsp[d]; vin[d] = vp[d]; }
  float* ko = khat + (size_t)u*8;
  float* vo = vhat + (size_t)u*8;
#pragma unroll
  for (int d = 0; d < 8; ++d){
    float ka = 0.0f, va = 0.0f;
#pragma unroll
    for (int d0 = 0; d0 < 8; ++d0){ ka += kin[d0]*wk[d0*8+d]; va += vin[d0]*wv[d0*8+d]; }
    ko[d] = ka; vo[d] = va;
  }
}

// ---------------- sr attention: block=(b,t,h), lane=r; loop n -------------------
__global__ __launch_bounds__(64) void k_attn_sr(
    const float* __restrict__ khat, const float* __restrict__ vhat,
    const float* __restrict__ qhat, const int* __restrict__ adj_sr,
    bf16* __restrict__ att_c, float* __restrict__ pre)
{
  int bid = blockIdx.x;
  int b = bid >> 10, th = bid & 1023;
  int t = th >> 3, h = th & 7;
  int r = threadIdx.x;
  float q[8];
#pragma unroll
  for (int d = 0; d < 8; ++d) q[d] = qhat[r*Ec + h*8 + d];
  float acc[8] = {0,0,0,0,0,0,0,0};
  for (int n = 0; n < Nc; ++n){
    size_t go = ((size_t)((b*Nc + n)*Tc + t))*Ec + h*8;
    float e = 0.0f;
#pragma unroll
    for (int d = 0; d < 8; ++d) e += q[d]*khat[go + d];
    int mflag = adj_sr[n*Rc + r];
    e = mflag ? clip5(e*0.125f) : -5.0f;
    float mx = wave_max64(e);
    float p = __expf(e - mx);
    float s = wave_sum64(p);
    float a = p / s;
    att_c[((size_t)(b*Nc + n)*THc + th)*Rc + r] = f2b(a);   // [B][N][TH][R]
#pragma unroll
    for (int d = 0; d < 8; ++d) acc[d] += a * vhat[go + d];
  }
  size_t po = ((size_t)((b*Rc + r)*Tc + t))*Ec + h*8;        // [B][R][T][E]
#pragma unroll
  for (int d = 0; d < 8; ++d) pre[po + d] = acc[d];
}

// ---------------- rr attention: block=(b,t,h), lane=q; loop k -------------------
__global__ __launch_bounds__(64) void k_attn_rr(
    const float* __restrict__ qh, const float* __restrict__ kh,
    const float* __restrict__ vh, const int* __restrict__ adj_r,
    bf16* __restrict__ att_c, float* __restrict__ pre)
{
  int bid = blockIdx.x;
  int b = bid >> 10, th = bid & 1023;
  int t = th >> 3, h = th & 7;
  int q = threadIdx.x;
  size_t qo = ((size_t)((b*Rc + q)*Tc + t))*Ec + h*8;
  float qv[8];
#pragma unroll
  for (int d = 0; d < 8; ++d) qv[d] = qh[qo + d];
  float acc[8] = {0,0,0,0,0,0,0,0};
  for (int k = 0; k < Rc; ++k){
    size_t ko = ((size_t)((b*Rc + k)*Tc + t))*Ec + h*8;
    float e = 0.0f;
#pragma unroll
    for (int d = 0; d < 8; ++d) e += qv[d]*kh[ko + d];
    int mflag = adj_r[q*Rc + k];
    e = mflag ? clip5(e*0.125f) : -5.0f;
    float mx = wave_max64(e);
    float p = __expf(e - mx);
    float s = wave_sum64(p);
    float a = p / s;
    att_c[((size_t)(b*Rc + k)*THc + th)*Rc + q] = f2b(a);   // [B][K][TH][Q=64]
#pragma unroll
    for (int d = 0; d < 8; ++d) acc[d] += a * vh[ko + d];
  }
#pragma unroll
  for (int d = 0; d < 8; ++d) pre[qo + d] = acc[d];          // [B][R][T][E]
}

// ---------------- rs attention: block=(b,t,h) x 512 thr, thread=q ---------------
__global__ __launch_bounds__(512) void k_attn_rs(
    const float* __restrict__ query, const float* __restrict__ ds,
    const float* __restrict__ Wq, const float* __restrict__ kh,
    const float* __restrict__ vh, bf16* __restrict__ att_c, float* __restrict__ pre)
{
  __shared__ float wq[64];
  __shared__ float kl[64][8];
  __shared__ float vl[64][8];
  __shared__ float redA[8];
  __shared__ float redB[8];
  int bid = blockIdx.x;
  int b = bid >> 10, th = bid & 1023;
  int t = th >> 3, h = th & 7;
  int q = threadIdx.x;
  if (q < 64) wq[q] = Wq[q];
  {
    int kk = q >> 3, d = q & 7;
    size_t o = ((size_t)((b*Rc + kk)*Tc + t))*Ec + h*8 + d;
    kl[kk][d] = kh[o];
    vl[kk][d] = vh[o];
  }
  __syncthreads();
  size_t qro = ((size_t)((b*Nc + q)*Tc + t))*Ec + h*8;
  const float* dsp = ds + q*Ec + h*8;
  float xin[8], qv[8];
#pragma unroll
  for (int d = 0; d < 8; ++d) xin[d] = query[qro + d] + dsp[d];
#pragma unroll
  for (int d = 0; d < 8; ++d){
    float a = 0.0f;
#pragma unroll
    for (int d0 = 0; d0 < 8; ++d0) a += xin[d0]*wq[d0*8 + d];
    qv[d] = a;
  }
  float acc[8] = {0,0,0,0,0,0,0,0};
  int lane = q & 63, wv = q >> 6;
  for (int k = 0; k < Rc; ++k){
    float e = 0.0f;
#pragma unroll
    for (int d = 0; d < 8; ++d) e += qv[d]*kl[k][d];
    e = clip5(e*0.125f);
    float mx = wave_max64(e);
    if (lane == 0) redA[wv] = mx;
    __syncthreads();
    float mall = redA[0];
#pragma unroll
    for (int i = 1; i < 8; ++i) mall = fmaxf(mall, redA[i]);
    float p = __expf(e - mall);
    float s = wave_sum64(p);
    if (lane == 0) redB[wv] = s;
    __syncthreads();
    float stot = 0.0f;
#pragma unroll
    for (int i = 0; i < 8; ++i) stot += redB[i];
    float a = p / stot;
    att_c[((size_t)(b*Rc + k)*THc + th)*Nc + q] = f2b(a);   // [B][K][TH][Q=512]
#pragma unroll
    for (int d = 0; d < 8; ++d) acc[d] += a * vl[k][d];
  }
#pragma unroll
  for (int d = 0; d < 8; ++d) pre[qro + d] = acc[d];         // [B][N][T][E]
}

// ---- transpose+widen: src bf16 [B][W][TH][C] -> dst fp32 [((b*C+c)*W+w)*TH+th] --
__global__ __launch_bounds__(256) void k_transpose(
    const unsigned short* __restrict__ src, float* __restrict__ dst,
    int W, int C)
{
  __shared__ unsigned short tile[64][66];
  int bid = blockIdx.x;
  int nct = C >> 6;
  int ct = bid % nct; bid /= nct;
  int tht = bid & 15; bid >>= 4;
  int w = bid % W; int b = bid / W;
  int tt = threadIdx.x;
  {
    int cs = tt & 63, i0 = tt >> 6;
    const unsigned short* sb = src + ((size_t)(b*W + w)*THc + tht*64)*C + ct*64;
#pragma unroll
    for (int p = 0; p < 16; ++p){
      int i = i0 + p*4;
      tile[i][cs] = sb[(size_t)i*C + cs];
    }
  }
  __syncthreads();
  {
    int i = tt & 63, c0 = tt >> 6;
#pragma unroll
    for (int p = 0; p < 16; ++p){
      int cs = c0 + p*4;
      int c = ct*64 + cs;
      dst[((size_t)(b*C + c)*W + w)*THc + tht*64 + i] = us2f(tile[i][cs]);
    }
  }
}

// ---------------- Wo projection: wave per row, row @ Wo + bo --------------------
__global__ __launch_bounds__(256) void k_wo(
    const float* __restrict__ pre, const float* __restrict__ Wo,
    const float* __restrict__ bo, float* __restrict__ outf,
    float* __restrict__ outf2, int nrows)
{
  int gt = blockIdx.x*256 + threadIdx.x;
  int row = gt >> 6, lane = gt & 63;
  if (row >= nrows) return;
  float xin = pre[(size_t)row*64 + lane];
  float acc = bo[lane];
  for (int e = 0; e < 64; ++e){
    float xe = __shfl(xin, e, 64);
    acc += xe * Wo[e*64 + lane];
  }
  outf[(size_t)row*64 + lane] = acc;
  if (outf2) outf2[(size_t)row*64 + lane] = acc;
}

// ---------------- per-head triple projection from [rows][64] fp32 ---------------
__global__ __launch_bounds__(256) void k_proj3(
    const float* __restrict__ src, const float* Wq, const float* Wk, const float* Wv,
    float* qh, float* kh, float* vh, int nunits)
{
  __shared__ float wq[64], wk[64], wv[64];
  int t = threadIdx.x;
  if (t < 64){
    wq[t] = Wq ? Wq[t] : 0.0f;
    wk[t] = Wk[t];
    wv[t] = Wv[t];
  }
  __syncthreads();
  int u = blockIdx.x*256 + t;
  if (u >= nunits) return;
  const float* sp = src + (size_t)u*8;
  float xin[8];
#pragma unroll
  for (int d = 0; d < 8; ++d) xin[d] = sp[d];
#pragma unroll
  for (int d = 0; d < 8; ++d){
    float qa = 0.0f, ka = 0.0f, va = 0.0f;
#pragma unroll
    for (int d0 = 0; d0 < 8; ++d0){
      qa += xin[d0]*wq[d0*8 + d];
      ka += xin[d0]*wk[d0*8 + d];
      va += xin[d0]*wv[d0*8 + d];
    }
    if (qh) qh[(size_t)u*8 + d] = qa;
    kh[(size_t)u*8 + d] = ka;
    vh[(size_t)u*8 + d] = va;
  }
}

// ---------------- fused tail: Wo_rs + LN1 + FF + LN2 + W_fs ---------------------
__global__ __launch_bounds__(256) void k_tail(
    const float* __restrict__ pre3, const float* __restrict__ query,
    const float* __restrict__ ds,
    const float* __restrict__ Wo, const float* __restrict__ bo,
    const float* __restrict__ g1, const float* __restrict__ be1,
    const float* __restrict__ W1, const float* __restrict__ b1,
    const float* __restrict__ W2, const float* __restrict__ b2,
    const float* __restrict__ g2, const float* __restrict__ be2,
    const float* __restrict__ Wfs, const float* __restrict__ bfs,
    float* __restrict__ outp)
{
  int tid = threadIdx.x;
  int lane = tid & 63, wv = tid >> 6;
  int row_base = blockIdx.x * 64;
  for (int it = 0; it < 16; ++it){
    int row = row_base + it*4 + wv;          // (b*N + n)*T + t
    int n = (row >> 7) & (Nc - 1);
    float a_in = pre3[(size_t)row*64 + lane];
    float attn = bo[lane];
#pragma unroll 16
    for (int e = 0; e < 64; ++e){
      float xe = __shfl(a_in, e, 64);
      attn += xe * Wo[e*64 + lane];
    }
    float qv = query[(size_t)row*64 + lane] + ds[n*64 + lane];
    float v0 = attn + qv;
    float m  = wave_sum64(v0) * (1.0f/64.0f);
    float c  = v0 - m;
    float var = wave_sum64(c*c) * (1.0f/64.0f);
    float x  = c * rsqrtf(var + 1e-5f) * g1[lane] + be1[lane];
    float hd[4];
#pragma unroll
    for (int j = 0; j < 4; ++j) hd[j] = b1[j*64 + lane];
#pragma unroll 8
    for (int e = 0; e < 64; ++e){
      float xe = __shfl(x, e, 64);
#pragma unroll
      for (int j = 0; j < 4; ++j) hd[j] += xe * W1[e*FFc + j*64 + lane];
    }
#pragma unroll
    for (int j = 0; j < 4; ++j) hd[j] = fmaxf(hd[j], 0.0f);
    float ff = b2[lane];
#pragma unroll
    for (int j = 0; j < 4; ++j){
#pragma unroll 16
      for (int l = 0; l < 64; ++l){
        float hv = __shfl(hd[j], l, 64);
        ff += hv * W2[(j*64 + l)*64 + lane];
      }
    }
    float u0 = ff + x;
    float m2 = wave_sum64(u0) * (1.0f/64.0f);
    float c2 = u0 - m2;
    float var2 = wave_sum64(c2*c2) * (1.0f/64.0f);
    float U = c2 * rsqrtf(var2 + 1e-5f) * g2[lane] + be2[lane];
    float o = bfs[lane];
#pragma unroll 16
    for (int e = 0; e < 64; ++e){
      float ue = __shfl(U, e, 64);
      o += ue * Wfs[e*64 + lane];
    }
    outp[(size_t)row*64 + lane] = o;
  }
}

extern "C" void kernel_launch(void* const* d_in, const int* in_sizes, int n_in,
                              void* d_out, int out_size, void* d_ws, size_t ws_size,
                              hipStream_t stream)
{
  const float* value = (const float*)d_in[0];
  const float* key   = (const float*)d_in[1];
  const float* query = (const float*)d_in[2];
  const int*  adj_sr = (const int*)d_in[3];
  const int*  adj_r  = (const int*)d_in[4];
  const float* D_S   = (const float*)d_in[5];
  const float* W_emb = (const float*)d_in[6];
  const float* b_emb = (const float*)d_in[7];
  const float* I_par = (const float*)d_in[8];
  const float* g1    = (const float*)d_in[9];
  const float* be1   = (const float*)d_in[10];
  const float* g2    = (const float*)d_in[11];
  const float* be2   = (const float*)d_in[12];
  const float* W_ff1 = (const float*)d_in[13];
  const float* b_ff1 = (const float*)d_in[14];
  const float* W_ff2 = (const float*)d_in[15];
  const float* b_ff2 = (const float*)d_in[16];
  const float* W_fs  = (const float*)d_in[17];
  const float* b_fs  = (const float*)d_in[18];
  const float* Wv_sr = (const float*)d_in[19];
  const float* Wk_sr = (const float*)d_in[20];
  const float* Wq_sr = (const float*)d_in[21];
  const float* Wo_sr = (const float*)d_in[22];
  const float* bo_sr = (const float*)d_in[23];
  const float* Wv_rr = (const float*)d_in[24];
  const float* Wk_rr = (const float*)d_in[25];
  const float* Wq_rr = (const float*)d_in[26];
  const float* Wo_rr = (const float*)d_in[27];
  const float* bo_rr = (const float*)d_in[28];
  const float* Wv_rs = (const float*)d_in[29];
  const float* Wk_rs = (const float*)d_in[30];
  const float* Wq_rs = (const float*)d_in[31];
  const float* Wo_rs = (const float*)d_in[32];
  const float* bo_rs = (const float*)d_in[33];

  float* outp  = (float*)d_out;
  float* o_out = outp;
  float* o_asr = outp + 8388608;
  float* o_arr = outp + 75497472;
  float* o_ars = outp + 83886080;
  float* o_hh  = outp + 150994944;

  // ---- workspace overlay (lifetime-checked), total 200.2 MB ----
  float* wsf = (float*)d_ws;
  float* ws_ds   = wsf;                      // 32768 floats, persistent
  float* ws_qsr  = wsf + 32768;              // 4096
  bf16*  ws_att  = (bf16*)(wsf + 36864);     // 67,108,864 bf16 = 33,554,432 floats
  float* pool    = wsf + 36864 + 33554432;   // stage-local scratch pool
  // stage 1
  float* ws_ksr  = pool;                     // 8,388,608
  float* ws_vsr  = pool + 8388608;           // 8,388,608
  float* ws_pre1 = pool + 16777216;          // 1,048,576
  float* ws_hh1  = pool + 17825792;          // 1,048,576
  // stage 2 (ksr/vsr dead by now)
  float* ws_qrr  = pool;                     // 1,048,576
  float* ws_krr  = pool + 1048576;
  float* ws_vrr  = pool + 2097152;
  float* ws_pre2 = pool + 3145728;
  float* ws_hh2  = pool + 4194304;
  // stage 3
  float* ws_krs  = pool + 5242880;
  float* ws_vrs  = pool + 6291456;
  float* ws_pre3 = pool + 7340032;           // 8,388,608

  // ---- stage 1: sr attention ----
  k_prep<<<576, 64, 0, stream>>>(D_S, W_emb, b_emb, I_par, Wq_sr, ws_ds, ws_qsr);
  k_proj_sr<<<4096, 256, 0, stream>>>(key, value, ws_ds, Wk_sr, Wv_sr, ws_ksr, ws_vsr);
  k_attn_sr<<<2048, 64, 0, stream>>>(ws_ksr, ws_vsr, ws_qsr, adj_sr, ws_att, ws_pre1);
  k_transpose<<<16384, 256, 0, stream>>>((const unsigned short*)ws_att, o_asr, 512, 64);
  k_wo<<<4096, 256, 0, stream>>>(ws_pre1, Wo_sr, bo_sr, ws_hh1, (float*)nullptr, 16384);

  // ---- stage 2: rr attention ----
  k_proj3<<<512, 256, 0, stream>>>(ws_hh1, Wq_rr, Wk_rr, Wv_rr,
                                   ws_qrr, ws_krr, ws_vrr, 131072);
  k_attn_rr<<<2048, 64, 0, stream>>>(ws_qrr, ws_krr, ws_vrr, adj_r, ws_att, ws_pre2);
  k_transpose<<<2048, 256, 0, stream>>>((const unsigned short*)ws_att, o_arr, 64, 64);
  k_wo<<<4096, 256, 0, stream>>>(ws_pre2, Wo_rr, bo_rr, ws_hh2, o_hh, 16384);

  // ---- stage 3: rs attention ----
  k_proj3<<<512, 256, 0, stream>>>(ws_hh2, (const float*)nullptr, Wk_rs, Wv_rs,
                                   (float*)nullptr, ws_krs, ws_vrs, 131072);
  k_attn_rs<<<2048, 512, 0, stream>>>(query, ws_ds, Wq_rs, ws_krs, ws_vrs,
                                      ws_att, ws_pre3);
  k_transpose<<<16384, 256, 0, stream>>>((const unsigned short*)ws_att, o_ars, 64, 512);

  // ---- tail: Wo_rs + LN + FF + LN + W_fs ----
  k_tail<<<2048, 256, 0, stream>>>(ws_pre3, query, ws_ds, Wo_rs, bo_rs,
                                   g1, be1, W_ff1, b_ff1, W_ff2, b_ff2,
                                   g2, be2, W_fs, b_fs, o_out);
}